// Round 1
// baseline (5532.435 us; speedup 1.0000x reference)
//
#include <hip/hip_runtime.h>

#define D 128
#define NTILE 32

// ---------------------------------------------------------------------------
// Kernel 0: W [o][k] -> Wt [k][o]  (one-time, 64 KB)
// ---------------------------------------------------------------------------
__global__ void k_transpose_w(const float* __restrict__ W, float* __restrict__ Wt) {
    int idx = blockIdx.x * blockDim.x + threadIdx.x;
    if (idx < D * D) {
        int o = idx >> 7;
        int k = idx & (D - 1);
        Wt[k * D + o] = W[idx];
    }
}

// ---------------------------------------------------------------------------
// Kernel 1: h = x @ W^T   (h[n][o] = sum_k x[n][k] * W[o][k])
// Block: 256 threads, tile = 32 nodes x 128 outs.
// Wt staged in LDS as [k][o] (64 KB): inner b128 reads are lane-stride 16 B
// -> conflict-free. x read from global: address uniform per half-wave
// (broadcast coalesce), tile read exactly once per block.
// Thread (to = t&31, tn = t>>5) computes nodes tn*4..+3  x  outs to*4..+3.
// ---------------------------------------------------------------------------
__global__ __launch_bounds__(256, 2) void k_gemm(const float* __restrict__ x,
                                                 const float* __restrict__ Wt,
                                                 float* __restrict__ h) {
    __shared__ float wt[D * D];
    int t = threadIdx.x;

    const float4* Wt4 = (const float4*)Wt;
    float4* wt4 = (float4*)wt;
#pragma unroll
    for (int i = 0; i < (D * D / 4) / 256; i++)
        wt4[t + i * 256] = Wt4[t + i * 256];
    __syncthreads();

    const int n0 = blockIdx.x * NTILE;
    const int to = t & 31;
    const int tn = t >> 5;

    float acc[4][4];
#pragma unroll
    for (int a = 0; a < 4; a++)
#pragma unroll
        for (int b = 0; b < 4; b++) acc[a][b] = 0.0f;

    const float* xb = x + (size_t)(n0 + tn * 4) * D;

    for (int k = 0; k < D; k += 4) {
        float4 xa[4], wb[4];
#pragma unroll
        for (int j = 0; j < 4; j++)
            xa[j] = *(const float4*)(xb + (size_t)j * D + k);
#pragma unroll
        for (int kk = 0; kk < 4; kk++)
            wb[kk] = *(const float4*)&wt[(k + kk) * D + to * 4];
#pragma unroll
        for (int j = 0; j < 4; j++) {
            acc[j][0] += xa[j].x * wb[0].x + xa[j].y * wb[1].x + xa[j].z * wb[2].x + xa[j].w * wb[3].x;
            acc[j][1] += xa[j].x * wb[0].y + xa[j].y * wb[1].y + xa[j].z * wb[2].y + xa[j].w * wb[3].y;
            acc[j][2] += xa[j].x * wb[0].z + xa[j].y * wb[1].z + xa[j].z * wb[2].z + xa[j].w * wb[3].z;
            acc[j][3] += xa[j].x * wb[0].w + xa[j].y * wb[1].w + xa[j].z * wb[2].w + xa[j].w * wb[3].w;
        }
    }

    float* hb = h + (size_t)(n0 + tn * 4) * D + to * 4;
#pragma unroll
    for (int j = 0; j < 4; j++) {
        float4 r;
        r.x = acc[j][0]; r.y = acc[j][1]; r.z = acc[j][2]; r.w = acc[j][3];
        *(float4*)(hb + (size_t)j * D) = r;
    }
}

// ---------------------------------------------------------------------------
// Kernel 2: out[dst] += h[src] over all edges.
// One wave handles 2 edges per iteration: half-wave (32 lanes) covers 128
// features as float4 (16 B/lane gather), then 4 fp32 atomicAdds per lane.
// ---------------------------------------------------------------------------
__global__ void k_scatter(const float* __restrict__ h, const int* __restrict__ src,
                          const int* __restrict__ dst, float* __restrict__ out, int E) {
    const int lane = threadIdx.x & 63;
    const int wave = (blockIdx.x * blockDim.x + threadIdx.x) >> 6;
    const int nwaves = (gridDim.x * blockDim.x) >> 6;
    const int sub = lane >> 5;        // which of the 2 edges
    const int f4 = (lane & 31) << 2;  // feature offset (float4 slot)

    for (int e = wave * 2 + sub; e < E; e += nwaves * 2) {
        int s = src[e];
        int d = dst[e];
        float4 v = *(const float4*)(h + (size_t)s * D + f4);
        float* op = out + (size_t)d * D + f4;
        atomicAdd(op + 0, v.x);
        atomicAdd(op + 1, v.y);
        atomicAdd(op + 2, v.z);
        atomicAdd(op + 3, v.w);
    }
}

extern "C" void kernel_launch(void* const* d_in, const int* in_sizes, int n_in,
                              void* d_out, int out_size, void* d_ws, size_t ws_size,
                              hipStream_t stream) {
    const float* x = (const float*)d_in[0];   // [N, 128]
    const float* W = (const float*)d_in[1];   // [128, 128]
    const int* ei  = (const int*)d_in[2];     // [2, E] flat
    float* out = (float*)d_out;               // [N, 128]

    const int N = in_sizes[0] / D;            // 100000
    const int E = in_sizes[2] / 2;            // 3200000

    float* Wt = (float*)d_ws;                 // 128*128 floats = 64 KB
    float* h  = (float*)d_ws + D * D;         // N*128 floats = 51.2 MB

    // zero the output accumulator (harness poisons it to 0xAA each call)
    hipMemsetAsync(d_out, 0, (size_t)out_size * sizeof(float), stream);

    k_transpose_w<<<(D * D + 255) / 256, 256, 0, stream>>>(W, Wt);
    k_gemm<<<N / NTILE, 256, 0, stream>>>(x, Wt, h);

    const int* srcp = ei;
    const int* dstp = ei + E;
    k_scatter<<<8192, 256, 0, stream>>>(h, srcp, dstp, out, E);
}

// Round 2
// 1029.257 us; speedup vs baseline: 5.3752x; 5.3752x over previous
//
#include <hip/hip_runtime.h>

#define D 128
#define NTILE 32

// ---------------------------------------------------------------------------
// Kernel 0: W [o][k] -> Wt [k][o]  (one-time, 64 KB)
// ---------------------------------------------------------------------------
__global__ void k_transpose_w(const float* __restrict__ W, float* __restrict__ Wt) {
    int idx = blockIdx.x * blockDim.x + threadIdx.x;
    if (idx < D * D) {
        int o = idx >> 7;
        int k = idx & (D - 1);
        Wt[k * D + o] = W[idx];
    }
}

// ---------------------------------------------------------------------------
// Kernel 1: h = x @ W^T  (register-tiled fp32, 32 nodes x 128 outs per block)
// ---------------------------------------------------------------------------
__global__ __launch_bounds__(256, 2) void k_gemm(const float* __restrict__ x,
                                                 const float* __restrict__ Wt,
                                                 float* __restrict__ h) {
    __shared__ float wt[D * D];
    int t = threadIdx.x;

    const float4* Wt4 = (const float4*)Wt;
    float4* wt4 = (float4*)wt;
#pragma unroll
    for (int i = 0; i < (D * D / 4) / 256; i++)
        wt4[t + i * 256] = Wt4[t + i * 256];
    __syncthreads();

    const int n0 = blockIdx.x * NTILE;
    const int to = t & 31;
    const int tn = t >> 5;

    float acc[4][4];
#pragma unroll
    for (int a = 0; a < 4; a++)
#pragma unroll
        for (int b = 0; b < 4; b++) acc[a][b] = 0.0f;

    const float* xb = x + (size_t)(n0 + tn * 4) * D;

    for (int k = 0; k < D; k += 4) {
        float4 xa[4], wb[4];
#pragma unroll
        for (int j = 0; j < 4; j++)
            xa[j] = *(const float4*)(xb + (size_t)j * D + k);
#pragma unroll
        for (int kk = 0; kk < 4; kk++)
            wb[kk] = *(const float4*)&wt[(k + kk) * D + to * 4];
#pragma unroll
        for (int j = 0; j < 4; j++) {
            acc[j][0] += xa[j].x * wb[0].x + xa[j].y * wb[1].x + xa[j].z * wb[2].x + xa[j].w * wb[3].x;
            acc[j][1] += xa[j].x * wb[0].y + xa[j].y * wb[1].y + xa[j].z * wb[2].y + xa[j].w * wb[3].y;
            acc[j][2] += xa[j].x * wb[0].z + xa[j].y * wb[1].z + xa[j].z * wb[2].z + xa[j].w * wb[3].z;
            acc[j][3] += xa[j].x * wb[0].w + xa[j].y * wb[1].w + xa[j].z * wb[2].w + xa[j].w * wb[3].w;
        }
    }

    float* hb = h + (size_t)(n0 + tn * 4) * D + to * 4;
#pragma unroll
    for (int j = 0; j < 4; j++) {
        float4 r;
        r.x = acc[j][0]; r.y = acc[j][1]; r.z = acc[j][2]; r.w = acc[j][3];
        *(float4*)(hb + (size_t)j * D) = r;
    }
}

// ---------------------------------------------------------------------------
// Kernel 2: histogram of dst
// ---------------------------------------------------------------------------
__global__ void k_hist(const int* __restrict__ dst, int* __restrict__ counts, int E) {
    int i = blockIdx.x * blockDim.x + threadIdx.x;
    int stride = gridDim.x * blockDim.x;
    for (int e = i; e < E; e += stride) atomicAdd(&counts[dst[e]], 1);
}

// ---------------------------------------------------------------------------
// Kernel 3: exclusive scan of counts[n] -> offsets[n+1], and cursor copy.
// Single block of 1024 threads; each thread owns a contiguous chunk.
// ---------------------------------------------------------------------------
__global__ __launch_bounds__(1024) void k_scan(const int* __restrict__ counts,
                                               int* __restrict__ offsets,
                                               int* __restrict__ cursor, int n) {
    __shared__ int sums[1024];
    const int t = threadIdx.x;
    const int chunk = (n + 1023) / 1024;
    const int start = t * chunk;
    const int end = min(start + chunk, n);

    int s = 0;
    for (int i = start; i < end; i++) s += counts[i];
    sums[t] = s;
    __syncthreads();

    // Hillis-Steele inclusive scan over 1024 partials
    for (int off = 1; off < 1024; off <<= 1) {
        int v = (t >= off) ? sums[t - off] : 0;
        __syncthreads();
        sums[t] += v;
        __syncthreads();
    }

    int base = sums[t] - s;  // exclusive prefix for this thread's chunk
    for (int i = start; i < end; i++) {
        offsets[i] = base;
        cursor[i] = base;
        base += counts[i];
    }
    if (t == 1023) offsets[n] = sums[1023];
}

// ---------------------------------------------------------------------------
// Kernel 4: bin src indices by dst
// ---------------------------------------------------------------------------
__global__ void k_sort(const int* __restrict__ src, const int* __restrict__ dst,
                       int* __restrict__ cursor, int* __restrict__ sorted_src, int E) {
    int i = blockIdx.x * blockDim.x + threadIdx.x;
    int stride = gridDim.x * blockDim.x;
    for (int e = i; e < E; e += stride) {
        int d = dst[e];
        int pos = atomicAdd(&cursor[d], 1);
        sorted_src[pos] = src[e];
    }
}

// ---------------------------------------------------------------------------
// Kernel 5: out[i] = sum over its binned edges of h[src].
// One half-wave (32 lanes) per output node; float4 per lane covers D=128.
// Register accumulation; each out row written exactly once; no atomics.
// ---------------------------------------------------------------------------
__global__ __launch_bounds__(256) void k_gather(const float* __restrict__ h,
                                                const int* __restrict__ sorted_src,
                                                const int* __restrict__ offsets,
                                                float* __restrict__ out, int N) {
    const int half = (blockIdx.x * blockDim.x + threadIdx.x) >> 5;
    if (half >= N) return;
    const int f4 = (threadIdx.x & 31) << 2;

    const int beg = offsets[half];
    const int end = offsets[half + 1];

    float4 a0 = {0.f, 0.f, 0.f, 0.f};
    float4 a1 = {0.f, 0.f, 0.f, 0.f};

    int j = beg;
    for (; j + 1 < end; j += 2) {
        int s0 = sorted_src[j];
        int s1 = sorted_src[j + 1];
        float4 v0 = *(const float4*)(h + (size_t)s0 * D + f4);
        float4 v1 = *(const float4*)(h + (size_t)s1 * D + f4);
        a0.x += v0.x; a0.y += v0.y; a0.z += v0.z; a0.w += v0.w;
        a1.x += v1.x; a1.y += v1.y; a1.z += v1.z; a1.w += v1.w;
    }
    if (j < end) {
        int s0 = sorted_src[j];
        float4 v0 = *(const float4*)(h + (size_t)s0 * D + f4);
        a0.x += v0.x; a0.y += v0.y; a0.z += v0.z; a0.w += v0.w;
    }

    float4 r;
    r.x = a0.x + a1.x; r.y = a0.y + a1.y; r.z = a0.z + a1.z; r.w = a0.w + a1.w;
    *(float4*)(out + (size_t)half * D + f4) = r;
}

extern "C" void kernel_launch(void* const* d_in, const int* in_sizes, int n_in,
                              void* d_out, int out_size, void* d_ws, size_t ws_size,
                              hipStream_t stream) {
    const float* x = (const float*)d_in[0];   // [N, 128]
    const float* W = (const float*)d_in[1];   // [128, 128]
    const int* ei  = (const int*)d_in[2];     // [2, E] flat
    float* out = (float*)d_out;               // [N, 128]

    const int N = in_sizes[0] / D;            // 100000
    const int E = in_sizes[2] / 2;            // 3200000

    const int* srcp = ei;
    const int* dstp = ei + E;

    // workspace layout (16B-aligned slabs)
    char* ws = (char*)d_ws;
    float* Wt = (float*)ws;                            ws += (size_t)D * D * 4;        // 64 KB
    float* h = (float*)ws;                             ws += (size_t)N * D * 4;        // 51.2 MB
    int* counts = (int*)ws;                            ws += (size_t)N * 4;            // 400 KB
    int* offsets = (int*)ws;                           ws += ((size_t)(N + 1) * 4 + 15) & ~15ull;
    int* cursor = (int*)ws;                            ws += (size_t)N * 4;
    int* sorted_src = (int*)ws;                        ws += (size_t)E * 4;            // 12.8 MB

    hipMemsetAsync(counts, 0, (size_t)N * 4, stream);

    k_transpose_w<<<(D * D + 255) / 256, 256, 0, stream>>>(W, Wt);
    k_gemm<<<N / NTILE, 256, 0, stream>>>(x, Wt, h);
    k_hist<<<4096, 256, 0, stream>>>(dstp, counts, E);
    k_scan<<<1, 1024, 0, stream>>>(counts, offsets, cursor, N);
    k_sort<<<4096, 256, 0, stream>>>(srcp, dstp, cursor, sorted_src, E);

    const int halves_per_block = 256 / 32;  // 8 nodes per block
    k_gather<<<(N + halves_per_block - 1) / halves_per_block, 256, 0, stream>>>(
        h, sorted_src, offsets, out, N);
}

// Round 3
// 501.022 us; speedup vs baseline: 11.0423x; 2.0543x over previous
//
#include <hip/hip_runtime.h>

#define D 128
#define NTILE 32

__device__ __forceinline__ unsigned short f2bf(float f) {
    union { float f; unsigned int u; } c; c.f = f;
    unsigned int b = c.u;
    unsigned int r = (b + 0x7FFFu + ((b >> 16) & 1u)) >> 16;  // RTN-even
    return (unsigned short)r;
}
__device__ __forceinline__ float bf2f(unsigned short s) {
    union { unsigned int u; float f; } c; c.u = ((unsigned int)s) << 16;
    return c.f;
}

// ---------------------------------------------------------------------------
// Kernel 0: W [o][k] -> Wt [k][o]  (one-time, 64 KB)
// ---------------------------------------------------------------------------
__global__ void k_transpose_w(const float* __restrict__ W, float* __restrict__ Wt) {
    int idx = blockIdx.x * blockDim.x + threadIdx.x;
    if (idx < D * D) {
        int o = idx >> 7;
        int k = idx & (D - 1);
        Wt[k * D + o] = W[idx];
    }
}

// ---------------------------------------------------------------------------
// Kernel 1: h = x @ W^T  (fp32 compute, bf16 output)
// 32 nodes x 128 outs per block; Wt staged in LDS [k][o].
// ---------------------------------------------------------------------------
__global__ __launch_bounds__(256, 2) void k_gemm(const float* __restrict__ x,
                                                 const float* __restrict__ Wt,
                                                 unsigned short* __restrict__ h) {
    __shared__ float wt[D * D];
    int t = threadIdx.x;

    const float4* Wt4 = (const float4*)Wt;
    float4* wt4 = (float4*)wt;
#pragma unroll
    for (int i = 0; i < (D * D / 4) / 256; i++)
        wt4[t + i * 256] = Wt4[t + i * 256];
    __syncthreads();

    const int n0 = blockIdx.x * NTILE;
    const int to = t & 31;
    const int tn = t >> 5;

    float acc[4][4];
#pragma unroll
    for (int a = 0; a < 4; a++)
#pragma unroll
        for (int b = 0; b < 4; b++) acc[a][b] = 0.0f;

    const float* xb = x + (size_t)(n0 + tn * 4) * D;

    for (int k = 0; k < D; k += 4) {
        float4 xa[4], wb[4];
#pragma unroll
        for (int j = 0; j < 4; j++)
            xa[j] = *(const float4*)(xb + (size_t)j * D + k);
#pragma unroll
        for (int kk = 0; kk < 4; kk++)
            wb[kk] = *(const float4*)&wt[(k + kk) * D + to * 4];
#pragma unroll
        for (int j = 0; j < 4; j++) {
            acc[j][0] += xa[j].x * wb[0].x + xa[j].y * wb[1].x + xa[j].z * wb[2].x + xa[j].w * wb[3].x;
            acc[j][1] += xa[j].x * wb[0].y + xa[j].y * wb[1].y + xa[j].z * wb[2].y + xa[j].w * wb[3].y;
            acc[j][2] += xa[j].x * wb[0].z + xa[j].y * wb[1].z + xa[j].z * wb[2].z + xa[j].w * wb[3].z;
            acc[j][3] += xa[j].x * wb[0].w + xa[j].y * wb[1].w + xa[j].z * wb[2].w + xa[j].w * wb[3].w;
        }
    }

    unsigned short* hb = h + (size_t)(n0 + tn * 4) * D + to * 4;
#pragma unroll
    for (int j = 0; j < 4; j++) {
        ushort4 r;
        r.x = f2bf(acc[j][0]); r.y = f2bf(acc[j][1]);
        r.z = f2bf(acc[j][2]); r.w = f2bf(acc[j][3]);
        *(ushort4*)(hb + (size_t)j * D) = r;
    }
}

// ---------------------------------------------------------------------------
// Kernel 2: build per-dst linked lists.
// next2[e] = {src[e], previous head of dst[e]}; sequential coalesced write.
// Only random traffic: atomicExch on 400 KB head array (cache-resident).
// ---------------------------------------------------------------------------
__global__ void k_build(const int* __restrict__ src, const int* __restrict__ dst,
                        int* __restrict__ head, int2* __restrict__ next2, int E) {
    int i = blockIdx.x * blockDim.x + threadIdx.x;
    int stride = gridDim.x * blockDim.x;
    for (int e = i; e < E; e += stride) {
        int s = src[e];
        int d = dst[e];
        int old = atomicExch(&head[d], e);
        next2[e] = make_int2(s, old);
    }
}

// ---------------------------------------------------------------------------
// Kernel 3: out[i] = sum over chain of h[src] (bf16 -> fp32 accumulate).
// One half-wave (32 lanes) per node; 4 bf16 (8 B) per lane covers D=128.
// 16K chains resident -> pointer-chase latency hidden; no atomics.
// ---------------------------------------------------------------------------
__global__ __launch_bounds__(256) void k_gather(const unsigned short* __restrict__ h,
                                                const int* __restrict__ head,
                                                const int2* __restrict__ next2,
                                                float* __restrict__ out, int N) {
    const int node = (blockIdx.x * blockDim.x + threadIdx.x) >> 5;
    if (node >= N) return;
    const int f = (threadIdx.x & 31) << 2;

    float4 acc = {0.f, 0.f, 0.f, 0.f};
    int e = head[node];
    while (e >= 0) {
        int2 p = next2[e];
        ushort4 v = *(const ushort4*)(h + (size_t)p.x * D + f);
        acc.x += bf2f(v.x);
        acc.y += bf2f(v.y);
        acc.z += bf2f(v.z);
        acc.w += bf2f(v.w);
        e = p.y;
    }
    *(float4*)(out + (size_t)node * D + f) = acc;
}

extern "C" void kernel_launch(void* const* d_in, const int* in_sizes, int n_in,
                              void* d_out, int out_size, void* d_ws, size_t ws_size,
                              hipStream_t stream) {
    const float* x = (const float*)d_in[0];   // [N, 128]
    const float* W = (const float*)d_in[1];   // [128, 128]
    const int* ei  = (const int*)d_in[2];     // [2, E] flat
    float* out = (float*)d_out;               // [N, 128]

    const int N = in_sizes[0] / D;            // 100000
    const int E = in_sizes[2] / 2;            // 3200000

    const int* srcp = ei;
    const int* dstp = ei + E;

    // workspace layout (16B-aligned slabs)
    char* ws = (char*)d_ws;
    float* Wt = (float*)ws;          ws += (size_t)D * D * 4;                    // 64 KB
    unsigned short* h = (unsigned short*)ws;
                                     ws += (size_t)N * D * 2;                    // 25.6 MB
    int* head = (int*)ws;            ws += ((size_t)N * 4 + 15) & ~15ull;        // 400 KB
    int2* next2 = (int2*)ws;         ws += (size_t)E * 8;                        // 25.6 MB

    hipMemsetAsync(head, 0xFF, (size_t)N * 4, stream);  // head = -1

    k_transpose_w<<<(D * D + 255) / 256, 256, 0, stream>>>(W, Wt);
    k_gemm<<<N / NTILE, 256, 0, stream>>>(x, Wt, h);
    k_build<<<4096, 256, 0, stream>>>(srcp, dstp, head, next2, E);

    const int nodes_per_block = 256 / 32;  // 8
    k_gather<<<(N + nodes_per_block - 1) / nodes_per_block, 256, 0, stream>>>(
        h, head, next2, out, N);
}